// Round 5
// baseline (390.111 us; speedup 1.0000x reference)
//
#include <hip/hip_runtime.h>
#include <math.h>

typedef unsigned int  u32;
typedef unsigned short u16;
typedef unsigned short u16x2 __attribute__((ext_vector_type(2)));

// ---------------- workspace layout (bytes) ----------------
// [0..40): 10 float max slots: 4 fw1max, 5 fw2max, 6 a1max, 7 a2max,
//          8 a3max, 9 a4max  (2,3 unused: w2/w3 max computed per-block)
// Slots never zeroed: ws poison 0xAAAAAAAA is a NEGATIVE int32; all stored
// values are float bits of v>=0, so int atomicMax is correct uninitialized.
// [64..320): 4 u32 barrier counters at 64B stride (zeroed by k_zero).
// Quantized weights (cross-block shared, published via barriers):
#define O_BARB   64
#define O_W2Q    4096      // u32[6400]   : w2 quant, [oc][tap][c16] packed
#define O_W3Q    32768     // u32[25600]  : w3 quant, [oc][tap][c32] packed
#define O_FW1Q   139264    // u32[131072] : fw1 quant, [o][k] pair-packed
#define O_FW2Q   663552    // u32[1280]   : fw2 quant, [o][k] pair-packed
#define NBLK     32u

__device__ __forceinline__ float blk_max(float v, float* red) {
  int t = threadIdx.x;
  __syncthreads();               // protect red[] reuse across calls
  red[t] = v;
  __syncthreads();
#pragma unroll
  for (int s = 128; s > 0; s >>= 1) {
    if (t < s) red[t] = fmaxf(red[t], red[t + s]);
    __syncthreads();
  }
  return red[0];
}

__device__ __forceinline__ void amax_f(float* slot, float v) {
  atomicMax((int*)slot, (int)__float_as_uint(v));   // v >= 0 always
}

__device__ __forceinline__ u16 quant1(float v, float s) {
  float q = rintf(v * s);
  q = fminf(fmaxf(q, 0.0f), 255.0f);
  return (u16)q;
}

// packed 2-MAC: acc += floor(a0*w0/256) + floor(a1*w1/256) in packed halves.
// products <= 255*255 fit u16 exactly; each 16-bit half accumulates <= 254/add.
__device__ __forceinline__ void mac_u32(u32& acc, u32 a, u32 w) {
  u16x2 av = __builtin_bit_cast(u16x2, a);
  u16x2 wv = __builtin_bit_cast(u16x2, w);
  u16x2 p  = av * wv;                    // v_pk_mul_lo_u16, exact
  acc += (__builtin_bit_cast(u32, p) >> 8) & 0x00FF00FFu;
}
__device__ __forceinline__ void mac4(u32& acc, uint4 a, uint4 w) {
  mac_u32(acc, a.x, w.x); mac_u32(acc, a.y, w.y);
  mac_u32(acc, a.z, w.z); mac_u32(acc, a.w, w.w);
}

__device__ __forceinline__ float fmax4(float4 v) {
  return fmaxf(fmaxf(fabsf(v.x), fabsf(v.y)), fmaxf(fabsf(v.z), fabsf(v.w)));
}

// Grid barrier among 32 blocks (one-shot; counters zeroed by k_zero).
// Residency validated by cooperative launch -> no deadlock. RELAXED poll
// (atomicity+agent scope bypass stale caches; no per-poll invalidate).
// Fencing: one release fence per block before arrival (L2 writeback), one
// acquire fence per block after the spin (L1/L2 invalidate) -> 32+32 fence
// ops per barrier instead of r4's 512+2048: the theory is the per-XCD
// writeback/invalidate serialization was the ~50us/barrier cost.
__device__ __forceinline__ void gbar(u32* cnt) {
  __syncthreads();
  if (threadIdx.x == 0) {
    __threadfence();                         // release: XCD L2 writeback
    __hip_atomic_fetch_add(cnt, 1u, __ATOMIC_RELEASE, __HIP_MEMORY_SCOPE_AGENT);
    while (__hip_atomic_load(cnt, __ATOMIC_RELAXED,
                             __HIP_MEMORY_SCOPE_AGENT) < NBLK)
      __builtin_amdgcn_s_sleep(8);
    __threadfence();                         // acquire: L1/L2 invalidate
  }
  __syncthreads();
}

// tiny zeroing kernel: clears the 4 barrier counters (64 words)
__global__ __launch_bounds__(256) void k_zero(u32* p) {
  if (threadIdx.x < 64) p[threadIdx.x] = 0;
}

// ---- one block per image: conv1 -> conv2 -> conv3 -> dense1 -> dense2,
//      activations resident in LDS the whole way.
__global__ __launch_bounds__(256) void k_fused(
    const float* __restrict__ x,
    const float* __restrict__ w1, const float* __restrict__ b1,
    const float* __restrict__ w2, const float* __restrict__ b2,
    const float* __restrict__ w3, const float* __restrict__ b3,
    const float* __restrict__ fw1, const float* __restrict__ fb1,
    const float* __restrict__ fw2, const float* __restrict__ fb2,
    float* __restrict__ out, float* wsf) {
  __shared__ float af[3136];        // persistent activations (a1/a2/a3 views)
  __shared__ float red[256];
  __shared__ float za4[256];        // a4
  __shared__ __align__(16) union {
    struct { unsigned char sx[1024]; u16 sw1[400]; } c1;                // 1824 B
    struct { u16 sa[324 * 16]; u16 sw2[12800]; int sconv[2][196]; } c2; // 37536 B
    struct { u16 sa3[121 * 40]; u16 sw3[3200]; } c3;                    // 16080 B
    struct { u16 sh[1024]; } d1;                                        // 2048 B
    struct { u16 sh2[256]; float z[16]; } d2;                           // 576 B
  } sm;
  const int t = threadIdx.x, bid = blockIdx.x;   // bid = image index, 0..31
  u32* bb    = (u32*)((char*)wsf + O_BARB);
  u32* w2q32 = (u32*)((char*)wsf + O_W2Q);
  u32* w3q32 = (u32*)((char*)wsf + O_W3Q);
  u32* fw1q32= (u32*)((char*)wsf + O_FW1Q);
  u32* fw2q32= (u32*)((char*)wsf + O_FW2Q);

  // ============ stage 0: scales + weight pre-quantization ============
  // Redundant per-block maxes (exact, deterministic, no barrier needed):
  float m = 0.f;
  const float4* x4 = (const float4*)x;
  for (int i = t; i < 6272; i += 256) m = fmaxf(m, fmax4(x4[i]));
  float xmax = blk_max(m, red);
  m = (t < 100) ? fmax4(((const float4*)w1)[t]) : 0.f;
  float w1max = blk_max(m, red);
  m = 0.f;
  const float4* w24 = (const float4*)w2;
  for (int i = t; i < 3200; i += 256) m = fmaxf(m, fmax4(w24[i]));
  float w2max = blk_max(m, red);
  m = 0.f;
  const float4* w34 = (const float4*)w3;
  for (int i = t; i < 12800; i += 256) m = fmaxf(m, fmax4(w34[i]));
  float w3max = blk_max(m, red);
  // Partitioned fw1/fw2 maxes (heavy reads): published at barrier A.
  m = 0.f;
  const float4* f14 = (const float4*)fw1;
  for (int i = bid * 256 + t; i < 65536; i += 8192) m = fmaxf(m, fmax4(f14[i]));
  m = blk_max(m, red);
  if (t == 0) amax_f(wsf + 4, m);
  m = 0.f;
  const float4* f24 = (const float4*)fw2;
  for (int i = bid * 256 + t; i < 640; i += 8192) m = fmaxf(m, fmax4(f24[i]));
  m = blk_max(m, red);
  if (t == 0) amax_f(wsf + 5, m);
  // Quantize w2/w3 into ws (each block 1/32, transposed [oc][tap][c] layout):
  {
    float s2w = 255.0f / fmaxf(w2max, 1e-6f);
    for (int i = bid * 256 + t; i < 6400; i += 8192) {
      int oc = i / 200, r = i - oc * 200, tp = r >> 3, c0 = (r & 7) * 2;
      w2q32[i] = (u32)quant1(w2[oc * 400 + c0 * 25 + tp], s2w)
               | ((u32)quant1(w2[oc * 400 + (c0 + 1) * 25 + tp], s2w) << 16);
    }
    float s3w = 255.0f / fmaxf(w3max, 1e-6f);
    for (int i = bid * 256 + t; i < 25600; i += 8192) {
      int oc = i / 400, r = i - oc * 400, tp = r >> 4, c0 = (r & 15) * 2;
      w3q32[i] = (u32)quant1(w3[oc * 800 + c0 * 25 + tp], s3w)
               | ((u32)quant1(w3[oc * 800 + (c0 + 1) * 25 + tp], s3w) << 16);
    }
  }

  // ============ stage 1: conv1 (all 16 oc, this image) ============
  {
    float s0  = 255.0f / fmaxf(xmax, 1e-6f);
    float sw1s = 255.0f / fmaxf(w1max, 1e-6f);
    u32* sxz = (u32*)sm.c1.sx;
    for (int i = t; i < 256; i += 256) sxz[i] = 0;
    __syncthreads();
    for (int i = t; i < 784; i += 256) {
      int y = i / 28, xx = i - y * 28;
      sm.c1.sx[(y + 2) * 32 + xx + 2] = (unsigned char)quant1(x[bid * 784 + i], s0);
    }
    for (int i = t; i < 400; i += 256)
      sm.c1.sw1[i] = quant1(w1[i], sw1s);
    __syncthreads();
    float lm = 0.f;
    if (t < 196) {
      int py = t / 14, px = t - py * 14;
      for (int oc = 0; oc < 16; ++oc) {
        int best = -2147483647;
#pragma unroll
        for (int dy = 0; dy < 2; ++dy)
#pragma unroll
          for (int dx = 0; dx < 2; ++dx) {
            int cy = 2 * py + dy, cx = 2 * px + dx;
            int acc = 0;
#pragma unroll
            for (int kh = 0; kh < 5; ++kh) {
              const unsigned char* xp = sm.c1.sx + (cy + kh) * 32 + cx;
#pragma unroll
              for (int kw = 0; kw < 5; ++kw)
                acc += ((int)xp[kw] * (int)sm.c1.sw1[oc * 25 + kh * 5 + kw]) >> 8;
            }
            best = max(best, acc);
          }
        float v = fmaxf(0.f, (float)best + b1[oc]);
        af[t * 16 + oc] = v;             // a1: [px][16c] in LDS
        lm = fmaxf(lm, v);
      }
    }
    lm = blk_max(lm, red);
    if (t == 0) amax_f(wsf + 6, lm);
  }
  gbar(bb + 0);   // A: a1max + fw-maxes + w2q/w3q published

  // ============ stage 2: conv2 (16->32) + fw1q/fw2q quantization ============
  {
    // fw1/fw2 pre-quantization (uses maxes published at A; consumed at >=C)
    {
      float sf1 = 255.0f / fmaxf(wsf[4], 1e-6f);
      const float2* f12 = (const float2*)fw1;
      for (int i = bid * 256 + t; i < 131072; i += 8192) {
        float2 f = f12[i];
        fw1q32[i] = (u32)quant1(f.x, sf1) | ((u32)quant1(f.y, sf1) << 16);
      }
      float sf2 = 255.0f / fmaxf(wsf[5], 1e-6f);
      const float2* f22 = (const float2*)fw2;
      for (int i = bid * 256 + t; i < 1280; i += 8192) {
        float2 f = f22[i];
        fw2q32[i] = (u32)quant1(f.x, sf2) | ((u32)quant1(f.y, sf2) << 16);
      }
    }
    float s1 = 255.0f / fmaxf(wsf[6], 1e-6f);
    u32* sz = (u32*)sm.c2.sa;
    for (int i = t; i < 2592; i += 256) sz[i] = 0;
    __syncthreads();
    for (int i = t; i < 3136; i += 256) {      // quantize a1 from LDS af
      int px = i >> 4, c = i & 15;
      int y = px / 14, xx = px - y * 14;
      sm.c2.sa[((y + 2) * 18 + xx + 2) * 16 + c] = quant1(af[i], s1);
    }
    u32* sw2z = (u32*)sm.c2.sw2;
    for (int i = t; i < 6400; i += 256) sw2z[i] = w2q32[i];  // all 32 oc
    __syncthreads();
    int h = t & 1, pxb = t >> 1;
    float lm = 0.f;
    for (int ocp = 0; ocp < 16; ++ocp) {
#pragma unroll
      for (int ol = 0; ol < 2; ++ol) {
        int oc = ocp * 2 + ol;
        const uint4* wq = (const uint4*)(sm.c2.sw2 + oc * 400);
#pragma unroll
        for (int rep = 0; rep < 2; ++rep) {
          int px = pxb + rep * 128;
          if (px < 196) {
            int y = px / 14, xx = px - y * 14;
            u32 acc = 0;                  // 100 packed adds * 254 < 2^16: exact
#pragma unroll
            for (int kh = 0; kh < 5; ++kh)
#pragma unroll
              for (int kw = 0; kw < 5; ++kw) {
                int row = (y + kh) * 18 + (xx + kw);
                uint4 av = *(const uint4*)(sm.c2.sa + row * 16 + h * 8);
                mac4(acc, av, wq[(kh * 5 + kw) * 2 + h]);
              }
            int ai = (int)((acc & 0xFFFFu) + (acc >> 16));
            ai += __shfl_down(ai, 1, 2);
            if (h == 0) sm.c2.sconv[ol][px] = ai;
          }
        }
      }
      __syncthreads();
      if (t < 49) {
        int py = t / 7, qx = t - py * 7;
#pragma unroll
        for (int ol = 0; ol < 2; ++ol) {
          int oc = ocp * 2 + ol;
          int mm = sm.c2.sconv[ol][(2 * py) * 14 + 2 * qx];
          mm = max(mm, sm.c2.sconv[ol][(2 * py) * 14 + 2 * qx + 1]);
          mm = max(mm, sm.c2.sconv[ol][(2 * py + 1) * 14 + 2 * qx]);
          mm = max(mm, sm.c2.sconv[ol][(2 * py + 1) * 14 + 2 * qx + 1]);
          float v = fmaxf(0.f, (float)mm + b2[oc]);
          af[t * 32 + oc] = v;           // a2: [49px][32c] in LDS
          lm = fmaxf(lm, v);
        }
      }
      __syncthreads();
    }
    lm = blk_max(lm, red);
    if (t == 0) amax_f(wsf + 7, lm);
  }
  gbar(bb + 1);   // B: a2max (+fw1q/fw2q published)

  // ============ stage 3: conv3 (32->64), pool pad=1 ============
  {
    float s2 = 255.0f / fmaxf(wsf[7], 1e-6f);
    u32* sz = (u32*)sm.c3.sa3;
    for (int i = t; i < 2420; i += 256) sz[i] = 0;
    __syncthreads();
    for (int i = t; i < 1568; i += 256) {      // quantize a2 from LDS af
      int px = i >> 5, c = i & 31;
      int y = px / 7, xx = px - y * 7;
      sm.c3.sa3[((y + 2) * 11 + xx + 2) * 40 + c] = quant1(af[i], s2);
    }
    __syncthreads();
    int q = t & 3, pos = t >> 2;
    int dydx = pos & 3, r = pos >> 2;
    int py = r >> 2, qx = r & 3;
    int cy = 2 * py - 1 + (dydx >> 1), cx = 2 * qx - 1 + (dydx & 1);
    bool valid = (cy >= 0 && cy < 7 && cx >= 0 && cx < 7);
    float lm = 0.f;
    u32* sw3z = (u32*)sm.c3.sw3;
    for (int og = 0; og < 16; ++og) {
      for (int i = t; i < 1600; i += 256) sw3z[i] = w3q32[og * 1600 + i];
      __syncthreads();
#pragma unroll
      for (int ol = 0; ol < 4; ++ol) {
        int oc = og * 4 + ol;
        int ai = 0;
        if (valid) {
          u32 acc = 0;                    // 100 packed adds: exact
#pragma unroll
          for (int kh = 0; kh < 5; ++kh)
#pragma unroll
            for (int kw = 0; kw < 5; ++kw) {
              int row = (cy + kh) * 11 + (cx + kw);
              uint4 av = *(const uint4*)(sm.c3.sa3 + row * 40 + q * 8);
              uint4 wv = *(const uint4*)(sm.c3.sw3 + (ol * 25 + kh * 5 + kw) * 32 + q * 8);
              mac4(acc, av, wv);
            }
          ai = (int)((acc & 0xFFFFu) + (acc >> 16));
        }
        ai += __shfl_down(ai, 2, 4);
        ai += __shfl_down(ai, 1, 4);
        int val = valid ? ai : -(1 << 30);
        int mm = max(val, __shfl_down(val, 4, 16));
        mm = max(mm, __shfl_down(mm, 8, 16));
        if ((t & 15) == 0) {
          float v = fmaxf(0.f, (float)mm + b3[oc]);
          af[oc * 16 + r] = v;           // a3: flatten (c, y, x) in LDS
          lm = fmaxf(lm, v);
        }
      }
      __syncthreads();
    }
    lm = blk_max(lm, red);
    if (t == 0) amax_f(wsf + 8, lm);
  }
  gbar(bb + 2);   // C: a3max

  // ============ stage 4: dense1 (1024->256) + relu ============
  {
    float s3 = 255.0f / fmaxf(wsf[8], 1e-6f);
    for (int i = t; i < 1024; i += 256)
      sm.d1.sh[i] = quant1(af[i], s3);
    __syncthreads();
    int ol = t >> 4, ks = t & 15;
    const uint4* hp = (const uint4*)sm.d1.sh;
    float lm = 0.f;
    for (int og = 0; og < 16; ++og) {
      int o = og * 16 + ol;
      const uint4* wq4 = (const uint4*)fw1q32 + o * 128;
      u32 acc = 0;                        // 64 packed adds: exact
#pragma unroll
      for (int j = 0; j < 8; ++j) {
        int e = j * 16 + ks;              // u16x8 chunk (k = 8e..8e+7)
        mac4(acc, hp[e], wq4[e]);
      }
      int ai = (int)((acc & 0xFFFFu) + (acc >> 16));
#pragma unroll
      for (int d = 8; d > 0; d >>= 1)
        ai += __shfl_down(ai, d, 16);
      if (ks == 0) {
        float v = fmaxf(0.f, (float)ai + fb1[o]);
        za4[o] = v;
        lm = fmaxf(lm, v);
      }
    }
    lm = blk_max(lm, red);
    if (t == 0) amax_f(wsf + 9, lm);
  }
  gbar(bb + 3);   // D: a4max

  // ============ stage 5: dense2 (256->10) + log_softmax ============
  {
    float s4 = 255.0f / fmaxf(wsf[9], 1e-6f);
    sm.d2.sh2[t] = quant1(za4[t], s4);
    __syncthreads();
    if (t < 40) {
      int o = t >> 2, ks = t & 3;
      const uint4* hp = (const uint4*)sm.d2.sh2;
      const uint4* wq2 = (const uint4*)fw2q32 + o * 32;
      u32 acc = 0;
#pragma unroll
      for (int j = 0; j < 8; ++j) {
        int e = j * 4 + ks;
        mac4(acc, hp[e], wq2[e]);
      }
      int ai = (int)((acc & 0xFFFFu) + (acc >> 16));
      ai += __shfl_down(ai, 2, 4);
      ai += __shfl_down(ai, 1, 4);
      if (ks == 0) sm.d2.z[o] = (float)ai + fb2[o];
    }
    __syncthreads();
    if (t < 10) {
      float mz = sm.d2.z[0];
#pragma unroll
      for (int j = 1; j < 10; ++j) mz = fmaxf(mz, sm.d2.z[j]);
      float se = 0.f;
#pragma unroll
      for (int j = 0; j < 10; ++j) se += expf(sm.d2.z[j] - mz);
      out[bid * 10 + t] = sm.d2.z[t] - (mz + logf(se));
    }
  }
}

extern "C" void kernel_launch(void* const* d_in, const int* in_sizes, int n_in,
                              void* d_out, int out_size, void* d_ws, size_t ws_size,
                              hipStream_t stream) {
  const float* x   = (const float*)d_in[0];
  // d_in[1] = lut, unused: lut[i][j] == (i*j)>>8 exactly, computed inline
  const float* w1  = (const float*)d_in[2];
  const float* b1  = (const float*)d_in[3];
  const float* w2  = (const float*)d_in[4];
  const float* b2  = (const float*)d_in[5];
  const float* w3  = (const float*)d_in[6];
  const float* b3  = (const float*)d_in[7];
  const float* fw1 = (const float*)d_in[8];
  const float* fb1 = (const float*)d_in[9];
  const float* fw2 = (const float*)d_in[10];
  const float* fb2 = (const float*)d_in[11];
  float* out = (float*)d_out;
  unsigned char* ws8 = (unsigned char*)d_ws;
  float* wsf = (float*)d_ws;
  u32* barp = (u32*)(ws8 + O_BARB);

  k_zero<<<1, 256, 0, stream>>>(barp);
  void* args[] = { &x, &w1, &b1, &w2, &b2, &w3, &b3,
                   &fw1, &fb1, &fw2, &fb2, &out, &wsf };
  hipLaunchCooperativeKernel((const void*)k_fused, dim3(32), dim3(256),
                             args, 0, stream);
}

// Round 6
// 175.561 us; speedup vs baseline: 2.2221x; 2.2221x over previous
//
#include <hip/hip_runtime.h>
#include <math.h>

typedef unsigned int  u32;
typedef unsigned long long u64;
typedef unsigned short u16;
typedef unsigned short u16x2 __attribute__((ext_vector_type(2)));

// ---------------- workspace layout (bytes) ----------------
// [0..40): 10 float max slots: 2 w2max, 3 w3max, 4 fw1max, 5 fw2max,
//          6 a1max, 7 a2max, 8 a3max, 9 a4max
// Slots never zeroed: ws poison 0xAAAAAAAA is a NEGATIVE int32; all stored
// values are float bits of v>=0, so int atomicMax is correct uninitialized.
#define O_A1     4096      // f32 [32][196][16]  (px-major, channel-last)
#define O_A2     405504    // f32 [32][49][32]
#define O_A3     606208    // f32 [32][1024]    (c*16 + y*4 + x flatten order)
#define O_A4     737280    // f32 [32][256]
// Barrier block (zeroed by k_zero):
//   roots: 4 x u32 at 64B stride  (+0 .. +255)
//   flag : 1 x u32                (+256)
//   leaves: 4 barriers x 64 leaves x u32 at 64B stride (+512 .. +16895)
#define O_BARB   770048
#define BAR_WORDS 4224     // 16896 B / 4
// fw1 pre-quantized (u16 [256][1024] = 512 KB), filled in stage 2
#define O_FW1Q   790528

#define NBLK     512u

// ---- coherence-point (Infinity Cache) access helpers ----
// Relaxed agent-scope atomics compile to global_load/store sc0 sc1: they
// bypass the non-coherent per-XCD L2s and complete at the memory-side L3.
// This gives cross-XCD visibility with NO fences (no buffer_wbl2/inv walks,
// which r2-r5 evidence pegs at ~50us per barrier).
__device__ __forceinline__ float ldf(const float* p) {
  return __hip_atomic_load(p, __ATOMIC_RELAXED, __HIP_MEMORY_SCOPE_AGENT);
}
__device__ __forceinline__ void stf(float* p, float v) {
  __hip_atomic_store(p, v, __ATOMIC_RELAXED, __HIP_MEMORY_SCOPE_AGENT);
}
__device__ __forceinline__ u64 ld8(const u64* p) {
  return __hip_atomic_load(p, __ATOMIC_RELAXED, __HIP_MEMORY_SCOPE_AGENT);
}
__device__ __forceinline__ void st4u(u32* p, u32 v) {
  __hip_atomic_store(p, v, __ATOMIC_RELAXED, __HIP_MEMORY_SCOPE_AGENT);
}

__device__ __forceinline__ float blk_max(float v, float* red) {
  int t = threadIdx.x;
  __syncthreads();               // protect red[] reuse across calls
  red[t] = v;
  __syncthreads();
#pragma unroll
  for (int s = 128; s > 0; s >>= 1) {
    if (t < s) red[t] = fmaxf(red[t], red[t + s]);
    __syncthreads();
  }
  return red[0];
}

__device__ __forceinline__ void amax_f(float* slot, float v) {
  atomicMax((int*)slot, (int)__float_as_uint(v));   // v >= 0 always; RMW at IF
}

__device__ __forceinline__ u16 quant1(float v, float s) {
  float q = rintf(v * s);
  q = fminf(fmaxf(q, 0.0f), 255.0f);
  return (u16)q;
}

// packed 2-MAC: acc += floor(a0*w0/256) + floor(a1*w1/256) in packed halves.
// products <= 255*255 fit u16 exactly; each 16-bit half accumulates <= 254/add.
__device__ __forceinline__ void mac_u32(u32& acc, u32 a, u32 w) {
  u16x2 av = __builtin_bit_cast(u16x2, a);
  u16x2 wv = __builtin_bit_cast(u16x2, w);
  u16x2 p  = av * wv;                    // v_pk_mul_lo_u16, exact
  acc += (__builtin_bit_cast(u32, p) >> 8) & 0x00FF00FFu;
}
__device__ __forceinline__ void mac4(u32& acc, uint4 a, uint4 w) {
  mac_u32(acc, a.x, w.x); mac_u32(acc, a.y, w.y);
  mac_u32(acc, a.z, w.z); mac_u32(acc, a.w, w.w);
}

__device__ __forceinline__ float fmax4(float4 v) {
  return fmaxf(fmaxf(fabsf(v.x), fabsf(v.y)), fmaxf(fabsf(v.z), fabsf(v.w)));
}

// Fence-free hierarchical one-shot grid barrier i (i = 0..3).
// Ordering argument: __syncthreads drains each wave's vmcnt before s_barrier,
// so ALL of the block's sc-bypass stores have completed at the coherence
// point before the leader's arrival increment. Consumers read exclusively
// via sc-bypass loads, so no invalidate is needed on the wait side.
// All RMWs/loads RELAXED -> no buffer_wbl2/buffer_inv anywhere.
__device__ __forceinline__ void gbar(int i, u32* bb) {
  __syncthreads();
  if (threadIdx.x == 0) {
    u32* root = bb + i * 16;                               // 64B stride
    u32* flag = bb + 64;
    u32* leaf = bb + 128 + (i * 64 + (int)(blockIdx.x >> 3)) * 16;
    asm volatile("s_waitcnt vmcnt(0)" ::: "memory");       // belt & braces
    u32 lo = __hip_atomic_fetch_add(leaf, 1u, __ATOMIC_RELAXED,
                                    __HIP_MEMORY_SCOPE_AGENT);
    if (lo == 7u) {
      u32 ro = __hip_atomic_fetch_add(root, 1u, __ATOMIC_RELAXED,
                                      __HIP_MEMORY_SCOPE_AGENT);
      if (ro == 63u)
        __hip_atomic_store(flag, (u32)(i + 1), __ATOMIC_RELAXED,
                           __HIP_MEMORY_SCOPE_AGENT);
    }
    while (__hip_atomic_load(flag, __ATOMIC_RELAXED,
                             __HIP_MEMORY_SCOPE_AGENT) < (u32)(i + 1))
      __builtin_amdgcn_s_sleep(2);
  }
  __syncthreads();
}

// tiny zeroing kernel: clears barrier counters before the fused kernel
__global__ __launch_bounds__(256) void k_zero(u32* p) {
  for (int i = threadIdx.x; i < BAR_WORDS; i += 256) p[i] = 0;
}

// ---- single fused kernel: conv1 -> conv2 -> conv3 -> dense1 -> dense2
__global__ __launch_bounds__(256, 2) void k_fused(
    const float* __restrict__ x,
    const float* __restrict__ w1, const float* __restrict__ b1,
    const float* __restrict__ w2, const float* __restrict__ b2,
    const float* __restrict__ w3, const float* __restrict__ b3,
    const float* __restrict__ fw1, const float* __restrict__ fb1,
    const float* __restrict__ fw2, const float* __restrict__ fb2,
    float* __restrict__ a1, float* __restrict__ a2,
    float* __restrict__ a3, float* __restrict__ a4,
    float* __restrict__ out, float* wsf) {
  __shared__ __align__(16) union {
    struct { unsigned char sx[1024]; u16 sw[64]; } c1;                 // 1152 B
    struct { u16 sa[324 * 16]; u16 sw[800]; int sconv[196]; } c2;      // 12752 B
    struct { u16 sa3[121 * 40]; u16 sw3[3200]; } c3;                   // 16080 B
    struct { u16 sh[1024]; } d1;                                       // 2048 B
    struct { u16 sh2[256]; float z[16]; } d2;                          // 576 B
  } sm;
  __shared__ float red[256];
  const int t = threadIdx.x, bid = blockIdx.x;
  u32* bb = (u32*)((char*)wsf + O_BARB);
  u32* fw1q32 = (u32*)((char*)wsf + O_FW1Q);

  // ============ stage 1: conv1 (blocks 0..255) + weight maxes (256..314) ====
  if (bid >= 256) {
    if (bid < 315) {
      int sb = bid - 256;
      const float* p; int n4, base, nb, slot;
      if (sb < 2)       { p = w2;  n4 = 3200;  base = sb;      nb = 2;  slot = 2; }
      else if (sb < 10) { p = w3;  n4 = 12800; base = sb - 2;  nb = 8;  slot = 3; }
      else if (sb < 58) { p = fw1; n4 = 65536; base = sb - 10; nb = 48; slot = 4; }
      else              { p = fw2; n4 = 640;   base = 0;       nb = 1;  slot = 5; }
      const float4* p4 = (const float4*)p;
      float m = 0.f;
      for (int i = base * 256 + t; i < n4; i += nb * 256) m = fmaxf(m, fmax4(p4[i]));
      m = blk_max(m, red);
      if (t == 0) amax_f(wsf + slot, m);
    }
    // blocks 315..511 idle this stage
  } else {
    int b = bid >> 3, op = bid & 7;    // oc = op*2, op*2+1
    // redundant global xmax (100 KB, L2-broadcast; same value in every block)
    float m = 0.f;
    const float4* x4 = (const float4*)x;
    for (int i = t; i < 6272; i += 256) m = fmaxf(m, fmax4(x4[i]));
    float xmax = blk_max(m, red);
    m = 0.f;
    if (t < 100) m = fmax4(((const float4*)w1)[t]);   // redundant w1max
    float w1max = blk_max(m, red);
    float s0  = 255.0f / fmaxf(xmax, 1e-6f);
    float sw1 = 255.0f / fmaxf(w1max, 1e-6f);

    u32* sxz = (u32*)sm.c1.sx;
    for (int i = t; i < 256; i += 256) sxz[i] = 0;
    __syncthreads();
    for (int i = t; i < 784; i += 256) {
      int y = i / 28, xx = i - y * 28;
      sm.c1.sx[(y + 2) * 32 + xx + 2] = (unsigned char)quant1(x[b * 784 + i], s0);
    }
    if (t < 50) sm.c1.sw[t] = quant1(w1[op * 50 + t], sw1);
    __syncthreads();
    float lm = 0.f;
    if (t < 196) {
      int py = t / 14, px = t - py * 14;
#pragma unroll
      for (int ol = 0; ol < 2; ++ol) {
        int oc = op * 2 + ol;
        int best = -2147483647;
#pragma unroll
        for (int dy = 0; dy < 2; ++dy)
#pragma unroll
          for (int dx = 0; dx < 2; ++dx) {
            int cy = 2 * py + dy, cx = 2 * px + dx;
            int acc = 0;
#pragma unroll
            for (int kh = 0; kh < 5; ++kh) {
              const unsigned char* xp = sm.c1.sx + (cy + kh) * 32 + cx;
#pragma unroll
              for (int kw = 0; kw < 5; ++kw)
                acc += ((int)xp[kw] * (int)sm.c1.sw[ol * 25 + kh * 5 + kw]) >> 8;
            }
            best = max(best, acc);
          }
        float v = fmaxf(0.f, (float)best + b1[oc]);
        stf(a1 + b * 3136 + t * 16 + oc, v);   // [b][px][16c] channel-last
        lm = fmaxf(lm, v);
      }
    }
    lm = blk_max(lm, red);
    if (t == 0) amax_f(wsf + 6, lm);
  }
  gbar(0, bb);

  // ============ stage 2: conv2 (16->32); all 512 blocks = (b, og of 2 oc) ====
  {
    // fw1 pre-quantization (image-independent; consumed at stage 4).
    {
      float swsq = 255.0f / fmaxf(ldf(wsf + 4), 1e-6f);
      int i = bid * 256 + t;
      float2 f = ((const float2*)fw1)[i];
      st4u(fw1q32 + i, (u32)quant1(f.x, swsq) | ((u32)quant1(f.y, swsq) << 16));
    }
    int b = bid >> 4, og = bid & 15;
    float s1 = 255.0f / fmaxf(ldf(wsf + 6), 1e-6f);
    float sw2s = 255.0f / fmaxf(ldf(wsf + 2), 1e-6f);
    u32* sz = (u32*)sm.c2.sa;
    for (int i = t; i < 2592; i += 256) sz[i] = 0;
    __syncthreads();
    const u64* a1u = (const u64*)(a1 + b * 3136);
    for (int i2 = t; i2 < 1568; i2 += 256) {     // a1 pairs via IF loads
      int px = i2 >> 3, c2 = i2 & 7;             // channels 2*c2, 2*c2+1
      int y = px / 14, xx = px - y * 14;
      float2 f = __builtin_bit_cast(float2, ld8(a1u + i2));
      u32 pk = (u32)quant1(f.x, s1) | ((u32)quant1(f.y, s1) << 16);
      ((u32*)sm.c2.sa)[((y + 2) * 18 + xx + 2) * 8 + c2] = pk;
    }
    for (int i = t; i < 800; i += 256) {
      int ol = i / 400, r = i - ol * 400, c = r / 25, tp = r - c * 25;
      sm.c2.sw[ol * 400 + tp * 16 + c] = quant1(w2[(og * 2 + ol) * 400 + c * 25 + tp], sw2s);
    }
    __syncthreads();
    int h = t & 1, pxb = t >> 1;
    float lm = 0.f;
    for (int ol = 0; ol < 2; ++ol) {
      int oc = og * 2 + ol;
      const uint4* wq = (const uint4*)(sm.c2.sw + ol * 400);
#pragma unroll
      for (int rep = 0; rep < 2; ++rep) {
        int px = pxb + rep * 128;
        if (px < 196) {
          int y = px / 14, xx = px - y * 14;
          u32 acc = 0;                  // 100 packed adds * 254 < 2^16: exact
#pragma unroll
          for (int kh = 0; kh < 5; ++kh)
#pragma unroll
            for (int kw = 0; kw < 5; ++kw) {
              int row = (y + kh) * 18 + (xx + kw);
              uint4 av = *(const uint4*)(sm.c2.sa + row * 16 + h * 8);
              mac4(acc, av, wq[(kh * 5 + kw) * 2 + h]);
            }
          int ai = (int)((acc & 0xFFFFu) + (acc >> 16));
          ai += __shfl_down(ai, 1, 2);
          if (h == 0) sm.c2.sconv[px] = ai;
        }
      }
      __syncthreads();
      if (t < 49) {
        int py = t / 7, px = t - py * 7;
        int mm = sm.c2.sconv[(2 * py) * 14 + 2 * px];
        mm = max(mm, sm.c2.sconv[(2 * py) * 14 + 2 * px + 1]);
        mm = max(mm, sm.c2.sconv[(2 * py + 1) * 14 + 2 * px]);
        mm = max(mm, sm.c2.sconv[(2 * py + 1) * 14 + 2 * px + 1]);
        float v = fmaxf(0.f, (float)mm + b2[oc]);
        stf(a2 + b * 1568 + t * 32 + oc, v);   // [b][px][32c]
        lm = fmaxf(lm, v);
      }
      __syncthreads();
    }
    lm = blk_max(lm, red);
    if (t == 0) amax_f(wsf + 7, lm);
  }
  gbar(1, bb);

  // ============ stage 3: conv3 (32->64), pool pad=1; (b, og of 4 oc) ========
  {
    int b = bid >> 4, og = bid & 15;
    float s2 = 255.0f / fmaxf(ldf(wsf + 7), 1e-6f);
    float sw3s = 255.0f / fmaxf(ldf(wsf + 3), 1e-6f);
    u32* sz = (u32*)sm.c3.sa3;
    for (int i = t; i < 2420; i += 256) sz[i] = 0;
    __syncthreads();
    const u64* a2u = (const u64*)(a2 + b * 1568);
    for (int i2 = t; i2 < 784; i2 += 256) {      // a2 pairs via IF loads
      int px = i2 >> 4, c2 = i2 & 15;            // channels 2*c2, 2*c2+1
      int y = px / 7, xx = px - y * 7;
      float2 f = __builtin_bit_cast(float2, ld8(a2u + i2));
      u32 pk = (u32)quant1(f.x, s2) | ((u32)quant1(f.y, s2) << 16);
      ((u32*)sm.c3.sa3)[((y + 2) * 11 + xx + 2) * 20 + c2] = pk;
    }
    for (int i = t; i < 3200; i += 256) {
      int ol = i / 800, r = i - ol * 800, c = r / 25, tp = r - c * 25;
      sm.c3.sw3[ol * 800 + tp * 32 + c] = quant1(w3[(og * 4 + ol) * 800 + c * 25 + tp], sw3s);
    }
    __syncthreads();
    int q = t & 3, pos = t >> 2;
    int dydx = pos & 3, r = pos >> 2;
    int py = r >> 2, px = r & 3;
    int cy = 2 * py - 1 + (dydx >> 1), cx = 2 * px - 1 + (dydx & 1);
    bool valid = (cy >= 0 && cy < 7 && cx >= 0 && cx < 7);
    float lm = 0.f;
    for (int ol = 0; ol < 4; ++ol) {
      int oc = og * 4 + ol;
      int ai = 0;
      if (valid) {
        u32 acc = 0;                    // 100 packed adds: exact
#pragma unroll
        for (int kh = 0; kh < 5; ++kh)
#pragma unroll
          for (int kw = 0; kw < 5; ++kw) {
            int row = (cy + kh) * 11 + (cx + kw);
            uint4 av = *(const uint4*)(sm.c3.sa3 + row * 40 + q * 8);
            uint4 wv = *(const uint4*)(sm.c3.sw3 + ol * 800 + (kh * 5 + kw) * 32 + q * 8);
            mac4(acc, av, wv);
          }
        ai = (int)((acc & 0xFFFFu) + (acc >> 16));
      }
      ai += __shfl_down(ai, 2, 4);
      ai += __shfl_down(ai, 1, 4);
      int val = valid ? ai : -(1 << 30);
      int mm = max(val, __shfl_down(val, 4, 16));
      mm = max(mm, __shfl_down(mm, 8, 16));
      if ((t & 15) == 0) {
        float v = fmaxf(0.f, (float)mm + b3[oc]);
        stf(a3 + b * 1024 + oc * 16 + r, v);   // flatten (c, y, x)
        lm = fmaxf(lm, v);
      }
    }
    lm = blk_max(lm, red);
    if (t == 0) amax_f(wsf + 8, lm);
  }
  gbar(2, bb);

  // ============ stage 4: dense1 (1024->256) + relu; (b, og of 16 oc) ========
  {
    int b = bid >> 4, og = bid & 15;
    float s3 = 255.0f / fmaxf(ldf(wsf + 8), 1e-6f);
    const u64* a3u = (const u64*)(a3 + b * 1024);
    for (int i2 = t; i2 < 512; i2 += 256) {      // a3 pairs via IF loads
      float2 f = __builtin_bit_cast(float2, ld8(a3u + i2));
      ((u32*)sm.d1.sh)[i2] = (u32)quant1(f.x, s3) | ((u32)quant1(f.y, s3) << 16);
    }
    __syncthreads();
    int ol = t >> 4, ks = t & 15;
    int o = og * 16 + ol;
    const u64* wq8 = (const u64*)fw1q32 + o * 256;  // [o][1024] u16 = 256 u64
    const uint4* hp = (const uint4*)sm.d1.sh;
    u32 acc = 0;                        // 64 packed adds: exact
#pragma unroll
    for (int j = 0; j < 8; ++j) {
      int e = j * 16 + ks;              // u16x8 chunk (k = 8e..8e+7)
      u64 w01 = ld8(wq8 + e * 2), w23 = ld8(wq8 + e * 2 + 1);
      uint4 wv;
      wv.x = (u32)w01; wv.y = (u32)(w01 >> 32);
      wv.z = (u32)w23; wv.w = (u32)(w23 >> 32);
      mac4(acc, hp[e], wv);
    }
    int ai = (int)((acc & 0xFFFFu) + (acc >> 16));
#pragma unroll
    for (int d = 8; d > 0; d >>= 1)
      ai += __shfl_down(ai, d, 16);
    float lm = 0.f;
    if (ks == 0) {
      float v = fmaxf(0.f, (float)ai + fb1[o]);
      stf(a4 + b * 256 + o, v);
      lm = v;
    }
    lm = blk_max(lm, red);
    if (t == 0) amax_f(wsf + 9, lm);
  }
  gbar(3, bb);

  // ============ stage 5: dense2 (256->10) + log_softmax (blocks 0..31) ======
  if (bid < 32) {
    int b = bid;
    float s4 = 255.0f / fmaxf(ldf(wsf + 9), 1e-6f);
    float sws = 255.0f / fmaxf(ldf(wsf + 5), 1e-6f);
    sm.d2.sh2[t] = quant1(ldf(a4 + b * 256 + t), s4);
    __syncthreads();
    if (t < 40) {
      int o = t >> 2, ks = t & 3;
      const float4* wf = (const float4*)(fw2 + o * 256);
      const uint4* hp = (const uint4*)sm.d2.sh2;
      u32 acc = 0;
#pragma unroll
      for (int j = 0; j < 8; ++j) {
        int e = j * 4 + ks;
        float4 f0 = wf[e * 2], f1 = wf[e * 2 + 1];
        uint4 wv;
        wv.x = (u32)quant1(f0.x, sws) | ((u32)quant1(f0.y, sws) << 16);
        wv.y = (u32)quant1(f0.z, sws) | ((u32)quant1(f0.w, sws) << 16);
        wv.z = (u32)quant1(f1.x, sws) | ((u32)quant1(f1.y, sws) << 16);
        wv.w = (u32)quant1(f1.z, sws) | ((u32)quant1(f1.w, sws) << 16);
        mac4(acc, hp[e], wv);
      }
      int ai = (int)((acc & 0xFFFFu) + (acc >> 16));
      ai += __shfl_down(ai, 2, 4);
      ai += __shfl_down(ai, 1, 4);
      if (ks == 0) sm.d2.z[o] = (float)ai + fb2[o];
    }
    __syncthreads();
    if (t < 10) {
      float mz = sm.d2.z[0];
#pragma unroll
      for (int j = 1; j < 10; ++j) mz = fmaxf(mz, sm.d2.z[j]);
      float se = 0.f;
#pragma unroll
      for (int j = 0; j < 10; ++j) se += expf(sm.d2.z[j] - mz);
      out[b * 10 + t] = sm.d2.z[t] - (mz + logf(se));
    }
  }
}

extern "C" void kernel_launch(void* const* d_in, const int* in_sizes, int n_in,
                              void* d_out, int out_size, void* d_ws, size_t ws_size,
                              hipStream_t stream) {
  const float* x   = (const float*)d_in[0];
  // d_in[1] = lut, unused: lut[i][j] == (i*j)>>8 exactly, computed inline
  const float* w1  = (const float*)d_in[2];
  const float* b1  = (const float*)d_in[3];
  const float* w2  = (const float*)d_in[4];
  const float* b2  = (const float*)d_in[5];
  const float* w3  = (const float*)d_in[6];
  const float* b3  = (const float*)d_in[7];
  const float* fw1 = (const float*)d_in[8];
  const float* fb1 = (const float*)d_in[9];
  const float* fw2 = (const float*)d_in[10];
  const float* fb2 = (const float*)d_in[11];
  float* out = (float*)d_out;
  unsigned char* ws8 = (unsigned char*)d_ws;
  float* wsf = (float*)d_ws;
  float* A1 = (float*)(ws8 + O_A1);
  float* A2 = (float*)(ws8 + O_A2);
  float* A3 = (float*)(ws8 + O_A3);
  float* A4 = (float*)(ws8 + O_A4);
  u32* barp = (u32*)(ws8 + O_BARB);

  k_zero<<<1, 256, 0, stream>>>(barp);
  void* args[] = { &x, &w1, &b1, &w2, &b2, &w3, &b3,
                   &fw1, &fb1, &fw2, &fb2,
                   &A1, &A2, &A3, &A4, &out, &wsf };
  hipLaunchCooperativeKernel((const void*)k_fused, dim3(512), dim3(256),
                             args, 0, stream);
}

// Round 9
// 140.526 us; speedup vs baseline: 2.7761x; 1.2493x over previous
//
#include <hip/hip_runtime.h>
#include <math.h>

typedef unsigned int  u32;
typedef unsigned short u16;
typedef unsigned short u16x2 __attribute__((ext_vector_type(2)));

// ---------------- workspace layout (bytes) ----------------
// [0..40): 10 float max slots: 2 w2max, 3 w3max, 4 fw1max, 5 fw2max,
//          6 a1max, 7 a2max, 8 a3max, 9 a4max
// Slots never zeroed: ws poison 0xAAAAAAAA is a NEGATIVE int32; all stored
// values are float bits of v>=0, so int atomicMax is correct uninitialized.
#define O_A1     4096      // f32 [32][196][16]  (px-major, channel-last)
#define O_A2     405504    // f32 [32][49][32]
#define O_A3     606208    // f32 [32][1024]    (c*16 + y*4 + x flatten order)
#define O_A4     737280    // f32 [32][256]
// fw1 pre-quantized (u16 [256][1024] = 512 KB), filled by k_conv2,
// consumed by k_dense1 (kernel boundary provides ordering + coherence).
#define O_FW1Q   770048

__device__ __forceinline__ float blk_max(float v, float* red) {
  int t = threadIdx.x;
  __syncthreads();               // protect red[] reuse across calls
  red[t] = v;
  __syncthreads();
#pragma unroll
  for (int s = 128; s > 0; s >>= 1) {
    if (t < s) red[t] = fmaxf(red[t], red[t + s]);
    __syncthreads();
  }
  return red[0];
}

__device__ __forceinline__ void amax_f(float* slot, float v) {
  atomicMax((int*)slot, (int)__float_as_uint(v));   // v >= 0 always
}

__device__ __forceinline__ u16 quant1(float v, float s) {
  float q = rintf(v * s);
  q = fminf(fmaxf(q, 0.0f), 255.0f);
  return (u16)q;
}

// packed 2-MAC: acc += floor(a0*w0/256) + floor(a1*w1/256) in packed halves.
// products <= 255*255 fit u16 exactly; each 16-bit half accumulates <= 254/add.
__device__ __forceinline__ void mac_u32(u32& acc, u32 a, u32 w) {
  u16x2 av = __builtin_bit_cast(u16x2, a);
  u16x2 wv = __builtin_bit_cast(u16x2, w);
  u16x2 p  = av * wv;                    // v_pk_mul_lo_u16, exact
  acc += (__builtin_bit_cast(u32, p) >> 8) & 0x00FF00FFu;
}
__device__ __forceinline__ void mac4(u32& acc, uint4 a, uint4 w) {
  mac_u32(acc, a.x, w.x); mac_u32(acc, a.y, w.y);
  mac_u32(acc, a.z, w.z); mac_u32(acc, a.w, w.w);
}

__device__ __forceinline__ float fmax4(float4 v) {
  return fmaxf(fmaxf(fabsf(v.x), fabsf(v.y)), fmaxf(fabsf(v.z), fabsf(v.w)));
}

// ---- kernel 1: conv1 (blocks 0..255, 2 oc each; xmax/w1max computed
//      REDUNDANTLY per block — exact, deterministic, no waits)
//      + spares 256..314: w2/w3/fw1/fw2 maxes (consumed after the kernel
//      boundary — nobody waits in-kernel).
__global__ __launch_bounds__(256) void k_conv1(
    const float* __restrict__ x, const float* __restrict__ w1, const float* __restrict__ b1,
    const float* __restrict__ w2, const float* __restrict__ w3,
    const float* __restrict__ fw1, const float* __restrict__ fw2,
    float* __restrict__ a1, float* wsf) {
  __shared__ unsigned char sx[1024];
  __shared__ u16 sw[64];
  __shared__ float red[256];
  const int t = threadIdx.x, bid = blockIdx.x;

  if (bid >= 256) {                  // weight-max spares
    int sb = bid - 256;
    const float* p; int n4, base, nb, slot;
    if (sb < 2)       { p = w2;  n4 = 3200;  base = sb;      nb = 2;  slot = 2; }
    else if (sb < 10) { p = w3;  n4 = 12800; base = sb - 2;  nb = 8;  slot = 3; }
    else if (sb < 58) { p = fw1; n4 = 65536; base = sb - 10; nb = 48; slot = 4; }
    else              { p = fw2; n4 = 640;   base = 0;       nb = 1;  slot = 5; }
    const float4* p4 = (const float4*)p;
    float m = 0.f;
    for (int i = base * 256 + t; i < n4; i += nb * 256) m = fmaxf(m, fmax4(p4[i]));
    m = blk_max(m, red);
    if (t == 0) amax_f(wsf + slot, m);
    return;
  }

  int b = bid >> 3, op = bid & 7;    // oc = op*2, op*2+1
  // redundant global xmax (100 KB, L2-broadcast; same value in every block)
  float m = 0.f;
  const float4* x4 = (const float4*)x;
  for (int i = t; i < 6272; i += 256) m = fmaxf(m, fmax4(x4[i]));
  float xmax = blk_max(m, red);
  m = 0.f;
  if (t < 100) m = fmax4(((const float4*)w1)[t]);   // redundant w1max
  float w1max = blk_max(m, red);
  float s0  = 255.0f / fmaxf(xmax, 1e-6f);
  float sw1 = 255.0f / fmaxf(w1max, 1e-6f);

  u32* sxz = (u32*)sx;
  for (int i = t; i < 256; i += 256) sxz[i] = 0;
  __syncthreads();
  for (int i = t; i < 784; i += 256) {
    int y = i / 28, xx = i - y * 28;
    sx[(y + 2) * 32 + xx + 2] = (unsigned char)quant1(x[b * 784 + i], s0);
  }
  if (t < 50) sw[t] = quant1(w1[op * 50 + t], sw1);
  __syncthreads();
  float lm = 0.f;
  if (t < 196) {
    int py = t / 14, px = t - py * 14;
#pragma unroll
    for (int ol = 0; ol < 2; ++ol) {
      int oc = op * 2 + ol;
      int best = -2147483647;
#pragma unroll
      for (int dy = 0; dy < 2; ++dy)
#pragma unroll
        for (int dx = 0; dx < 2; ++dx) {
          int cy = 2 * py + dy, cx = 2 * px + dx;
          int acc = 0;
#pragma unroll
          for (int kh = 0; kh < 5; ++kh) {
            const unsigned char* xp = sx + (cy + kh) * 32 + cx;
#pragma unroll
            for (int kw = 0; kw < 5; ++kw)
              acc += ((int)xp[kw] * (int)sw[ol * 25 + kh * 5 + kw]) >> 8;
          }
          best = max(best, acc);
        }
      float v = fmaxf(0.f, (float)best + b1[oc]);
      a1[b * 3136 + t * 16 + oc] = v;   // [b][px][16c] channel-last
      lm = fmaxf(lm, v);
    }
  }
  lm = blk_max(lm, red);
  if (t == 0) amax_f(wsf + 6, lm);
}

// ---- kernel 2: conv2 (16->32); 512 blocks=(b, og of 2 oc); 2 lanes/px
//      + fw1 pre-quantization (1/512 per block; consumed by k_dense1)
__global__ __launch_bounds__(256) void k_conv2(
    const float* __restrict__ a1, const float* __restrict__ w2, const float* __restrict__ b2,
    const float* __restrict__ fw1, u32* __restrict__ fw1q,
    float* __restrict__ a2, float* wsf) {
  __shared__ __align__(16) u16 sa[324 * 16];   // [18*18 px][16 ch]
  __shared__ __align__(16) u16 sw[800];        // [2 oc][25 tap][16 ch]
  __shared__ int sconv[196];
  __shared__ float red[256];
  const int t = threadIdx.x, bid = blockIdx.x;
  int b = bid >> 4, og = bid & 15;
  // fw1 pre-quantization chunk: values identical to what k_dense1 computed
  // inline in the baseline (same quant1, same wsf[4] scale) -> absmax 0.
  {
    float swsq = 255.0f / fmaxf(wsf[4], 1e-6f);
    int i = bid * 256 + t;
    float2 f = ((const float2*)fw1)[i];
    fw1q[i] = (u32)quant1(f.x, swsq) | ((u32)quant1(f.y, swsq) << 16);
  }
  float s1 = 255.0f / fmaxf(wsf[6], 1e-6f);
  float sw2 = 255.0f / fmaxf(wsf[2], 1e-6f);
  u32* sz = (u32*)sa;
  for (int i = t; i < 2592; i += 256) sz[i] = 0;
  __syncthreads();
  for (int i = t; i < 3136; i += 256) {        // a1 is [px][16c]: coalesced
    int px = i >> 4, c = i & 15;
    int y = px / 14, xx = px - y * 14;
    sa[((y + 2) * 18 + xx + 2) * 16 + c] = quant1(a1[b * 3136 + i], s1);
  }
  for (int i = t; i < 800; i += 256) {
    int ol = i / 400, r = i - ol * 400, c = r / 25, tp = r - c * 25;
    sw[ol * 400 + tp * 16 + c] = quant1(w2[(og * 2 + ol) * 400 + c * 25 + tp], sw2);
  }
  __syncthreads();
  int h = t & 1, pxb = t >> 1;
  float lm = 0.f;
  for (int ol = 0; ol < 2; ++ol) {
    int oc = og * 2 + ol;
    const uint4* wq = (const uint4*)(sw + ol * 400);
#pragma unroll
    for (int rep = 0; rep < 2; ++rep) {
      int px = pxb + rep * 128;
      if (px < 196) {
        int y = px / 14, xx = px - y * 14;
        u32 acc = 0;                  // 100 packed adds * 254 < 2^16: exact
#pragma unroll
        for (int kh = 0; kh < 5; ++kh)
#pragma unroll
          for (int kw = 0; kw < 5; ++kw) {
            int row = (y + kh) * 18 + (xx + kw);
            uint4 av = *(const uint4*)(sa + row * 16 + h * 8);
            mac4(acc, av, wq[(kh * 5 + kw) * 2 + h]);
          }
        int ai = (int)((acc & 0xFFFFu) + (acc >> 16));
        ai += __shfl_down(ai, 1, 2);
        if (h == 0) sconv[px] = ai;
      }
    }
    __syncthreads();
    if (t < 49) {
      int py = t / 7, px = t - py * 7;
      int mm = sconv[(2 * py) * 14 + 2 * px];
      mm = max(mm, sconv[(2 * py) * 14 + 2 * px + 1]);
      mm = max(mm, sconv[(2 * py + 1) * 14 + 2 * px]);
      mm = max(mm, sconv[(2 * py + 1) * 14 + 2 * px + 1]);
      float v = fmaxf(0.f, (float)mm + b2[oc]);
      a2[b * 1568 + t * 32 + oc] = v;   // [b][px][32c]
      lm = fmaxf(lm, v);
    }
    __syncthreads();
  }
  lm = blk_max(lm, red);
  if (t == 0) amax_f(wsf + 7, lm);
}

// ---- kernel 3: conv3 (32->64), pool pad=1; 512 blocks=(b, og of 4 oc); 4 lanes/pos
__global__ __launch_bounds__(256) void k_conv3(
    const float* __restrict__ a2, const float* __restrict__ w3, const float* __restrict__ b3,
    float* __restrict__ a3, float* wsf) {
  __shared__ __align__(16) u16 sa[121 * 40];   // [11*11 px][32 ch + 8 pad]
  __shared__ __align__(16) u16 sw[4 * 800];    // [4 oc][25 tap][32 ch]
  __shared__ float red[256];
  const int t = threadIdx.x, bid = blockIdx.x;
  int b = bid >> 4, og = bid & 15;
  float s2 = 255.0f / fmaxf(wsf[7], 1e-6f);
  float sw3 = 255.0f / fmaxf(wsf[3], 1e-6f);
  u32* sz = (u32*)sa;
  for (int i = t; i < 2420; i += 256) sz[i] = 0;
  __syncthreads();
  for (int i = t; i < 1568; i += 256) {        // a2 is [px][32c]: coalesced
    int px = i >> 5, c = i & 31;
    int y = px / 7, xx = px - y * 7;
    sa[((y + 2) * 11 + xx + 2) * 40 + c] = quant1(a2[b * 1568 + i], s2);
  }
  for (int i = t; i < 3200; i += 256) {
    int ol = i / 800, r = i - ol * 800, c = r / 25, tp = r - c * 25;
    sw[ol * 800 + tp * 32 + c] = quant1(w3[(og * 4 + ol) * 800 + c * 25 + tp], sw3);
  }
  __syncthreads();
  int q = t & 3, pos = t >> 2;
  int dydx = pos & 3, r = pos >> 2;
  int py = r >> 2, px = r & 3;
  int cy = 2 * py - 1 + (dydx >> 1), cx = 2 * px - 1 + (dydx & 1);
  bool valid = (cy >= 0 && cy < 7 && cx >= 0 && cx < 7);
  float lm = 0.f;
  for (int ol = 0; ol < 4; ++ol) {
    int oc = og * 4 + ol;
    int ai = 0;
    if (valid) {
      u32 acc = 0;                    // 100 packed adds: exact
#pragma unroll
      for (int kh = 0; kh < 5; ++kh)
#pragma unroll
        for (int kw = 0; kw < 5; ++kw) {
          int row = (cy + kh) * 11 + (cx + kw);
          uint4 av = *(const uint4*)(sa + row * 40 + q * 8);
          uint4 wv = *(const uint4*)(sw + ol * 800 + (kh * 5 + kw) * 32 + q * 8);
          mac4(acc, av, wv);
        }
      ai = (int)((acc & 0xFFFFu) + (acc >> 16));
    }
    ai += __shfl_down(ai, 2, 4);
    ai += __shfl_down(ai, 1, 4);
    int val = valid ? ai : -(1 << 30);
    int mm = max(val, __shfl_down(val, 4, 16));
    mm = max(mm, __shfl_down(mm, 8, 16));
    if ((t & 15) == 0) {
      float v = fmaxf(0.f, (float)mm + b3[oc]);
      a3[b * 1024 + oc * 16 + r] = v;   // flatten (c, y, x)
      lm = fmaxf(lm, v);
    }
  }
  lm = blk_max(lm, red);
  if (t == 0) amax_f(wsf + 8, lm);
}

// ---- kernel 4: dense1 (1024->256) + relu; 512 blocks=(b, og of 16 oc);
// consumes pre-quantized fw1q (u16) — no float weight loads, no inline quant.
__global__ __launch_bounds__(256) void k_dense1(
    const float* __restrict__ a3f, const u32* __restrict__ fw1q,
    const float* __restrict__ fb1,
    float* __restrict__ a4, float* wsf) {
  __shared__ __align__(16) u16 sh[1024];
  __shared__ float red[256];
  const int t = threadIdx.x, bid = blockIdx.x;
  int b = bid >> 4, og = bid & 15;
  float s3 = 255.0f / fmaxf(wsf[8], 1e-6f);
  for (int i = t; i < 1024; i += 256)
    sh[i] = quant1(a3f[b * 1024 + i], s3);
  __syncthreads();
  int ol = t >> 4, ks = t & 15;
  int o = og * 16 + ol;
  const uint4* wq4 = (const uint4*)fw1q + o * 128;  // [o][1024] u16, x8 chunks
  const uint4* hp = (const uint4*)sh;
  u32 acc = 0;                        // 64 packed adds: exact
#pragma unroll
  for (int j = 0; j < 8; ++j) {
    int e = j * 16 + ks;              // u16x8 chunk (k = 8e..8e+7)
    mac4(acc, hp[e], wq4[e]);
  }
  int ai = (int)((acc & 0xFFFFu) + (acc >> 16));
#pragma unroll
  for (int d = 8; d > 0; d >>= 1)
    ai += __shfl_down(ai, d, 16);
  float lm = 0.f;
  if (ks == 0) {
    float v = fmaxf(0.f, (float)ai + fb1[o]);
    a4[b * 256 + o] = v;
    lm = v;
  }
  lm = blk_max(lm, red);
  if (t == 0) amax_f(wsf + 9, lm);
}

// ---- kernel 5: dense2 (256->10) + log_softmax -> out (32,10)
__global__ __launch_bounds__(64) void k_dense2(
    const float* __restrict__ a4, const float* __restrict__ fw2, const float* __restrict__ fb2,
    float* __restrict__ out, float* wsf) {
  int b = blockIdx.x;
  __shared__ __align__(16) u16 sh[256];
  __shared__ float z[16];
  int t = threadIdx.x;
  float s4 = 255.0f / fmaxf(wsf[9], 1e-6f);
  float sws = 255.0f / fmaxf(wsf[5], 1e-6f);
  for (int i = t; i < 256; i += 64)
    sh[i] = quant1(a4[b * 256 + i], s4);
  __syncthreads();
  if (t < 40) {
    int o = t >> 2, ks = t & 3;
    const float4* wf = (const float4*)(fw2 + o * 256);
    const uint4* hp = (const uint4*)sh;
    u32 acc = 0;
#pragma unroll
    for (int j = 0; j < 8; ++j) {
      int e = j * 4 + ks;
      float4 f0 = wf[e * 2], f1 = wf[e * 2 + 1];
      uint4 wv;
      wv.x = (u32)quant1(f0.x, sws) | ((u32)quant1(f0.y, sws) << 16);
      wv.y = (u32)quant1(f0.z, sws) | ((u32)quant1(f0.w, sws) << 16);
      wv.z = (u32)quant1(f1.x, sws) | ((u32)quant1(f1.y, sws) << 16);
      wv.w = (u32)quant1(f1.z, sws) | ((u32)quant1(f1.w, sws) << 16);
      mac4(acc, hp[e], wv);
    }
    int ai = (int)((acc & 0xFFFFu) + (acc >> 16));
    ai += __shfl_down(ai, 2, 4);
    ai += __shfl_down(ai, 1, 4);
    if (ks == 0) z[o] = (float)ai + fb2[o];
  }
  __syncthreads();
  if (t < 10) {
    float m = z[0];
#pragma unroll
    for (int j = 1; j < 10; ++j) m = fmaxf(m, z[j]);
    float se = 0.f;
#pragma unroll
    for (int j = 0; j < 10; ++j) se += expf(z[j] - m);
    out[b * 10 + t] = z[t] - (m + logf(se));
  }
}

extern "C" void kernel_launch(void* const* d_in, const int* in_sizes, int n_in,
                              void* d_out, int out_size, void* d_ws, size_t ws_size,
                              hipStream_t stream) {
  const float* x   = (const float*)d_in[0];
  // d_in[1] = lut, unused: lut[i][j] == (i*j)>>8 exactly, computed inline
  const float* w1  = (const float*)d_in[2];
  const float* b1  = (const float*)d_in[3];
  const float* w2  = (const float*)d_in[4];
  const float* b2  = (const float*)d_in[5];
  const float* w3  = (const float*)d_in[6];
  const float* b3  = (const float*)d_in[7];
  const float* fw1 = (const float*)d_in[8];
  const float* fb1 = (const float*)d_in[9];
  const float* fw2 = (const float*)d_in[10];
  const float* fb2 = (const float*)d_in[11];
  float* out = (float*)d_out;
  unsigned char* ws8 = (unsigned char*)d_ws;
  float* wsf = (float*)d_ws;
  float* A1 = (float*)(ws8 + O_A1);
  float* A2 = (float*)(ws8 + O_A2);
  float* A3 = (float*)(ws8 + O_A3);
  float* A4 = (float*)(ws8 + O_A4);
  u32* FW1Q = (u32*)(ws8 + O_FW1Q);

  k_conv1 <<<315, 256, 0, stream>>>(x, w1, b1, w2, w3, fw1, fw2, A1, wsf);
  k_conv2 <<<512, 256, 0, stream>>>(A1, w2, b2, fw1, FW1Q, A2, wsf);
  k_conv3 <<<512, 256, 0, stream>>>(A2, w3, b3, A3, wsf);
  k_dense1<<<512, 256, 0, stream>>>(A3, FW1Q, fb1, A4, wsf);
  k_dense2<<<32, 64, 0, stream>>>(A4, fw2, fb2, out, wsf);
}